// Round 1
// baseline (1412.472 us; speedup 1.0000x reference)
//
#include <hip/hip_runtime.h>
#include <cmath>

#define SEQ 1024
#define HID 1024
#define NH  16
#define HD  64

// rotated LDS layout: element (row, d) of a 64-wide tile at row*64 + ((d+4*row)&63)
#define ROT(row, d) ((((row) << 6)) | ((((d) + ((row) << 2))) & 63))

__device__ __forceinline__ float dacc(float acc, float4 a, float4 b) {
    acc = fmaf(a.x, b.x, acc);
    acc = fmaf(a.y, b.y, acc);
    acc = fmaf(a.z, b.z, acc);
    acc = fmaf(a.w, b.w, acc);
    return acc;
}

// ---------------- Kernel 1: fused QKV projection ----------------
// C[m,o] = sum_i hs[m,i] * W[o,i] + b[o], scattered into Q/K/V [B][NH][S][HD]
// BM=BN=128, BK=16, 256 threads, 8x8 micro-tile per thread.
__global__ __launch_bounds__(256) void qkv_kernel(
    const float* __restrict__ hs, const float* __restrict__ W,
    const float* __restrict__ bias,
    float* __restrict__ Qo, float* __restrict__ Ko, float* __restrict__ Vo)
{
    // skewed layout: col -> col + ((col>>5)<<2); max index 139 -> stride 140
    __shared__ __align__(16) float As[16][140];
    __shared__ __align__(16) float Ws[16][140];

    const int t  = threadIdx.x;
    const int m0 = blockIdx.y * 128;
    const int o0 = blockIdx.x * 128;
    const int tn = t & 15, tm = t >> 4;
    const int kq = t & 3,  lrow = t >> 2;

    float acc[8][8];
#pragma unroll
    for (int i = 0; i < 8; ++i)
#pragma unroll
        for (int j = 0; j < 8; ++j) acc[i][j] = 0.f;

    const int sa = (8 * tm) + (((8 * tm) >> 5) << 2);
    const int sb = (8 * tn) + (((8 * tn) >> 5) << 2);

    for (int kb = 0; kb < HID; kb += 16) {
        __syncthreads();
#pragma unroll
        for (int half = 0; half < 2; ++half) {
            const int m  = lrow + 64 * half;
            const int sm = m + ((m >> 5) << 2);
            const float4 a = *(const float4*)(hs + (size_t)(m0 + m) * HID + kb + kq * 4);
            As[kq * 4 + 0][sm] = a.x;
            As[kq * 4 + 1][sm] = a.y;
            As[kq * 4 + 2][sm] = a.z;
            As[kq * 4 + 3][sm] = a.w;
            const float4 w = *(const float4*)(W + (size_t)(o0 + m) * HID + kb + kq * 4);
            Ws[kq * 4 + 0][sm] = w.x;
            Ws[kq * 4 + 1][sm] = w.y;
            Ws[kq * 4 + 2][sm] = w.z;
            Ws[kq * 4 + 3][sm] = w.w;
        }
        __syncthreads();
#pragma unroll
        for (int k = 0; k < 16; ++k) {
            const float4 a0 = *(const float4*)&As[k][sa];
            const float4 a1 = *(const float4*)&As[k][sa + 4];
            const float4 b0 = *(const float4*)&Ws[k][sb];
            const float4 b1 = *(const float4*)&Ws[k][sb + 4];
            const float am[8] = {a0.x, a0.y, a0.z, a0.w, a1.x, a1.y, a1.z, a1.w};
            const float bn[8] = {b0.x, b0.y, b0.z, b0.w, b1.x, b1.y, b1.z, b1.w};
#pragma unroll
            for (int i = 0; i < 8; ++i)
#pragma unroll
                for (int j = 0; j < 8; ++j)
                    acc[i][j] = fmaf(am[i], bn[j], acc[i][j]);
        }
    }

    // epilogue: bias add + scatter to [B][NH][S][HD]
#pragma unroll
    for (int i = 0; i < 8; ++i) {
        const int m = m0 + 8 * tm + i;
        const int b = m >> 10, s = m & 1023;
#pragma unroll
        for (int jq = 0; jq < 2; ++jq) {
            const int o = o0 + 8 * tn + jq * 4;
            float4 v;
            v.x = acc[i][jq * 4 + 0] + bias[o + 0];
            v.y = acc[i][jq * 4 + 1] + bias[o + 1];
            v.z = acc[i][jq * 4 + 2] + bias[o + 2];
            v.w = acc[i][jq * 4 + 3] + bias[o + 3];
            const int which = o >> 10;
            const int oh = (o & 1023) >> 6;
            const int d = o & 63;
            float* dst = (which == 0) ? Qo : (which == 1) ? Ko : Vo;
            *(float4*)(dst + (((size_t)(b * NH + oh) * SEQ + s) * HD + d)) = v;
        }
    }
}

// ---------------- Kernel 2: fused rel-pos attention (flash-style) ----------------
// block = 256 threads = (tl 0..15) x (tr 0..15); one block per (b, h, 32-row l-tile)
// scores: l = tl+16i (i<2), r = tr+16j (j<4); e-row sharing via i-j diagonal.
__global__ __launch_bounds__(256) void attn_kernel(
    const float* __restrict__ Q, const float* __restrict__ K,
    const float* __restrict__ V, const float* __restrict__ E,
    const float* __restrict__ mask, float* __restrict__ outp)
{
    __shared__ __align__(16) float Qs[32 * 64];
    __shared__ __align__(16) float Ks[64 * 64];
    __shared__ __align__(16) float Vs[64 * 64];
    __shared__ __align__(16) float Es[95 * 64];   // first 2048 floats reused as Ps

    const int t  = threadIdx.x;
    const int lt = blockIdx.x & 31;
    const int bh = blockIdx.x >> 5;
    const int b  = bh >> 4, h = bh & 15;
    const int l0 = lt << 5;
    const int tr = t & 15, tl = t >> 4;

    const float* Qg = Q + (((size_t)bh << 10) + l0) * HD;
    const float* Kg = K + ((size_t)bh << 16);
    const float* Vg = V + ((size_t)bh << 16);

    // stage Q (pre-scaled by 1/sqrt(64))
#pragma unroll
    for (int p = 0; p < 2; ++p) {
        const int idx = (p << 8) + t;
        const int row = idx >> 4, dc = (idx & 15) << 2;
        const float4 q = *(const float4*)(Qg + (row << 6) + dc);
        float* dst = &Qs[ROT(row, dc)];
        dst[0] = q.x * 0.125f; dst[1] = q.y * 0.125f;
        dst[2] = q.z * 0.125f; dst[3] = q.w * 0.125f;
    }

    float Ov[2][4] = {{0.f, 0.f, 0.f, 0.f}, {0.f, 0.f, 0.f, 0.f}};
    float mr[2] = {-1e30f, -1e30f};
    float lrun[2] = {0.f, 0.f};

    for (int r0 = 0; r0 < SEQ; r0 += 64) {
        __syncthreads();                       // A: prev PV done, buffers free
#pragma unroll
        for (int p = 0; p < 4; ++p) {
            const int idx = (p << 8) + t;
            const int row = idx >> 4, dc = (idx & 15) << 2;
            const float4 kv = *(const float4*)(Kg + (size_t)((r0 + row) << 6) + dc);
            float* kd = &Ks[ROT(row, dc)];
            kd[0] = kv.x; kd[1] = kv.y; kd[2] = kv.z; kd[3] = kv.w;
            const float4 vv = *(const float4*)(Vg + (size_t)((r0 + row) << 6) + dc);
            float* vd = &Vs[ROT(row, dc)];
            vd[0] = vv.x; vd[1] = vv.y; vd[2] = vv.z; vd[3] = vv.w;
        }
        {
            const int j0 = l0 - r0 + 960;      // e-band start, always in [0,1952]
            for (int idx = t; idx < 95 * 16; idx += 256) {
                const int row = idx >> 4, dc = (idx & 15) << 2;
                const float4 e = *(const float4*)(E + ((size_t)(j0 + row) << 6) + dc);
                float* ed = &Es[ROT(row, dc)];
                ed[0] = e.x; ed[1] = e.y; ed[2] = e.z; ed[3] = e.w;
            }
        }
        __syncthreads();                       // B: staging visible

        float a1[2][4] = {}, a2[2][4] = {}, a3[2][4] = {};
#pragma unroll
        for (int dc = 0; dc < 64; dc += 4) {
            float4 qf[2], kf[4], ef[5];
            qf[0] = *(const float4*)&Qs[ROT(tl, dc)];
            qf[1] = *(const float4*)&Qs[ROT(tl + 16, dc)];
#pragma unroll
            for (int j = 0; j < 4; ++j)
                kf[j] = *(const float4*)&Ks[ROT(tr + (j << 4), dc)];
#pragma unroll
            for (int k = 0; k < 5; ++k) {
                const int er = tl - tr + 15 + (k << 4);   // in [0,94]
                ef[k] = *(const float4*)&Es[ROT(er, dc)];
            }
#pragma unroll
            for (int i = 0; i < 2; ++i)
#pragma unroll
                for (int j = 0; j < 4; ++j) {
                    a1[i][j] = dacc(a1[i][j], qf[i], kf[j]);
                    const float4 e = ef[i - j + 3];
                    a2[i][j] = dacc(a2[i][j], qf[i], e);
                    a3[i][j] = dacc(a3[i][j], kf[j], e);
                }
        }

        // online softmax (row state replicated across the 16 lanes of each row group)
        float pv_[2][4];
#pragma unroll
        for (int i = 0; i < 2; ++i) {
            float sc[4], tmax = -1e30f;
#pragma unroll
            for (int j = 0; j < 4; ++j) {
                sc[j] = a1[i][j] + a2[i][j] + 0.125f * a3[i][j]
                      + mask[(b << 10) + r0 + tr + (j << 4)];
                tmax = fmaxf(tmax, sc[j]);
            }
            tmax = fmaxf(tmax, __shfl_xor(tmax, 1));
            tmax = fmaxf(tmax, __shfl_xor(tmax, 2));
            tmax = fmaxf(tmax, __shfl_xor(tmax, 4));
            tmax = fmaxf(tmax, __shfl_xor(tmax, 8));
            const float mnew  = fmaxf(mr[i], tmax);
            const float alpha = __expf(mr[i] - mnew);
            float ts = 0.f;
#pragma unroll
            for (int j = 0; j < 4; ++j) {
                pv_[i][j] = __expf(sc[j] - mnew);
                ts += pv_[i][j];
            }
            ts += __shfl_xor(ts, 1);
            ts += __shfl_xor(ts, 2);
            ts += __shfl_xor(ts, 4);
            ts += __shfl_xor(ts, 8);
            lrun[i] = lrun[i] * alpha + ts;
            mr[i]   = mnew;
#pragma unroll
            for (int c = 0; c < 4; ++c) Ov[i][c] *= alpha;
        }
        __syncthreads();                       // C: all Es reads done before overlay
        float* Ps = Es;                        // Ps overlays Es[0..2047]
#pragma unroll
        for (int i = 0; i < 2; ++i)
#pragma unroll
            for (int j = 0; j < 4; ++j)
                Ps[ROT(tl + (i << 4), tr + (j << 4))] = pv_[i][j];
        __syncthreads();                       // D: Ps visible

        // PV: thread owns rows l = tl+16i, d-chunk = 4*tr
#pragma unroll
        for (int rq = 0; rq < 64; rq += 4) {
            const float4 p0 = *(const float4*)&Ps[ROT(tl, rq)];
            const float4 p1 = *(const float4*)&Ps[ROT(tl + 16, rq)];
            const float pa[2][4] = {{p0.x, p0.y, p0.z, p0.w},
                                    {p1.x, p1.y, p1.z, p1.w}};
#pragma unroll
            for (int q = 0; q < 4; ++q) {
                const float4 vv = *(const float4*)&Vs[ROT(rq + q, tr << 2)];
#pragma unroll
                for (int i = 0; i < 2; ++i) {
                    Ov[i][0] = fmaf(pa[i][q], vv.x, Ov[i][0]);
                    Ov[i][1] = fmaf(pa[i][q], vv.y, Ov[i][1]);
                    Ov[i][2] = fmaf(pa[i][q], vv.z, Ov[i][2]);
                    Ov[i][3] = fmaf(pa[i][q], vv.w, Ov[i][3]);
                }
            }
        }
    }

    // normalize + write out[b, s, h*64+d]
#pragma unroll
    for (int i = 0; i < 2; ++i) {
        const float inv = 1.f / lrun[i];
        float4 o;
        o.x = Ov[i][0] * inv; o.y = Ov[i][1] * inv;
        o.z = Ov[i][2] * inv; o.w = Ov[i][3] * inv;
        *(float4*)(outp + ((size_t)(b << 10) + l0 + tl + (i << 4)) * HID
                        + (h << 6) + (tr << 2)) = o;
    }
}

extern "C" void kernel_launch(void* const* d_in, const int* in_sizes, int n_in,
                              void* d_out, int out_size, void* d_ws, size_t ws_size,
                              hipStream_t stream)
{
    const float* hs   = (const float*)d_in[0];   // [4,1024,1024]
    const float* qkvw = (const float*)d_in[1];   // [3072,1024]
    const float* qkvb = (const float*)d_in[2];   // [3072]
    const float* demb = (const float*)d_in[3];   // [2047,64]
    const float* mask = (const float*)d_in[4];   // [4,1,1,1024]
    float* out = (float*)d_out;

    const size_t per = (size_t)4 * NH * SEQ * HD; // 4,194,304 floats
    float* Qo = (float*)d_ws;
    float* Ko = Qo + per;
    float* Vo = Ko + per;

    dim3 g1(3072 / 128, 4096 / 128);   // 24 x 32
    qkv_kernel<<<g1, 256, 0, stream>>>(hs, qkvw, qkvb, Qo, Ko, Vo);

    dim3 g2(4 * NH * (SEQ / 32));      // 2048 blocks
    attn_kernel<<<g2, 256, 0, stream>>>(Qo, Ko, Vo, demb, mask, out);
}

// Round 2
// 241.330 us; speedup vs baseline: 5.8529x; 5.8529x over previous
//
#include <hip/hip_runtime.h>

#define SEQ 1024
#define NH  16

typedef __attribute__((ext_vector_type(8))) short short8;
typedef __attribute__((ext_vector_type(4))) float floatx4;
typedef __attribute__((ext_vector_type(4))) unsigned short ushortx4;

// async global->LDS, 16B per lane; LDS dest = wave-uniform base + lane*16
#define GLDS16(gp, lp) __builtin_amdgcn_global_load_lds( \
    (const __attribute__((address_space(1))) void*)(gp), \
    (__attribute__((address_space(3))) void*)(lp), 16, 0, 0)

__device__ __forceinline__ unsigned short f2b(float f) {   // fp32 -> bf16 RNE
    union { float f; unsigned u; } v; v.f = f;
    unsigned r = (v.u + 0x7fffu + ((v.u >> 16) & 1u)) >> 16;
    return (unsigned short)r;
}
__device__ __forceinline__ float b2f(unsigned short h) {
    union { unsigned u; float f; } v; v.u = ((unsigned)h) << 16;
    return v.f;
}

// swizzled addr helpers (element offsets in a 64-wide bf16 tile: 8 chunks of 16B/row)
#define TADDR(base, row, ch) ((base) + ((row) << 6) + ((((ch) ^ ((row) & 7))) << 3))
// U/W tiles [128 delta][64 x] bf16, 8B-group swizzle
#define UWADDR(dl, x) (((dl) << 6) + ((((x) >> 2) ^ ((dl) & 15)) << 2) + ((x) & 3))

// ---------------- k0: fp32 -> bf16 casts ----------------
__global__ void cast_kernel(const float* __restrict__ hs, const float* __restrict__ W,
                            const float* __restrict__ E,
                            unsigned short* __restrict__ hsb,
                            unsigned short* __restrict__ Wb,
                            unsigned short* __restrict__ Eb)
{
    const int QH = 1048576, QW = 786432, QE = 32752;   // quads
    const int NT = QH + QW + QE;
    for (int q = blockIdx.x * 256 + threadIdx.x; q < NT; q += gridDim.x * 256) {
        const float* src; unsigned short* dst; int off;
        if (q < QH)           { src = hs; dst = hsb; off = q; }
        else if (q < QH + QW) { src = W;  dst = Wb;  off = q - QH; }
        else                  { src = E;  dst = Eb;  off = q - QH - QW; }
        const float4 v = *(const float4*)(src + (size_t)off * 4);
        ushortx4 o; o[0] = f2b(v.x); o[1] = f2b(v.y); o[2] = f2b(v.z); o[3] = f2b(v.w);
        *(ushortx4*)(dst + (size_t)off * 4) = o;
    }
}

// ---------------- k1: QKV projection, bf16 MFMA, NT layout ----------------
// C[m,o] = sum_k hs[m,k]*W[o,k] + bias[o];  Q pre-scaled 0.125; V stored transposed [bh][d][s]
__global__ __launch_bounds__(256, 3) void qkv_gemm(
    const unsigned short* __restrict__ Ab, const unsigned short* __restrict__ Bb,
    const float* __restrict__ bias,
    unsigned short* __restrict__ Qb, unsigned short* __restrict__ Kb,
    unsigned short* __restrict__ Vt)
{
    __shared__ unsigned short sm[8192];          // A [0,4096), B [4096,8192) elems
    const int t = threadIdx.x, w = t >> 6;
    const int ln = t & 15, g = (t >> 4) & 3;
    const int wm = w >> 1, wn = w & 1;
    const int m0 = blockIdx.y << 7, o0 = blockIdx.x << 7;

    floatx4 acc[4][4];
#pragma unroll
    for (int i = 0; i < 4; ++i)
#pragma unroll
        for (int j = 0; j < 4; ++j) acc[i][j] = (floatx4){0.f, 0.f, 0.f, 0.f};

    auto stage = [&](int kb) {
#pragma unroll
        for (int p = 0; p < 2; ++p) {
            const int idx = (p << 8) + t;
            const int row = idx >> 2;
            const int c = (idx & 3) ^ ((row ^ (row >> 2)) & 3);
            GLDS16(Ab + (size_t)(m0 + row) * 1024 + kb + (c << 3),
                   (char*)sm + (p << 12) + (w << 10));
            GLDS16(Bb + (size_t)(o0 + row) * 1024 + kb + (c << 3),
                   (char*)sm + 8192 + (p << 12) + (w << 10));
        }
    };

    stage(0);
    for (int kb = 0;;) {
        __syncthreads();
        short8 af[4], bf_[4];
#pragma unroll
        for (int i = 0; i < 4; ++i) {
            const int r = (wm << 6) + (i << 4) + ln;
            af[i] = *(const short8*)&sm[(r << 5) + ((g ^ ((r ^ (r >> 2)) & 3)) << 3)];
        }
#pragma unroll
        for (int j = 0; j < 4; ++j) {
            const int r = (wn << 6) + (j << 4) + ln;
            bf_[j] = *(const short8*)&sm[4096 + (r << 5) + ((g ^ ((r ^ (r >> 2)) & 3)) << 3)];
        }
#pragma unroll
        for (int i = 0; i < 4; ++i)
#pragma unroll
            for (int j = 0; j < 4; ++j)
                acc[i][j] = __builtin_amdgcn_mfma_f32_16x16x32_bf16(af[i], bf_[j], acc[i][j], 0, 0, 0);
        kb += 32;
        if (kb >= 1024) break;
        __syncthreads();
        stage(kb);
    }

    const int which = o0 >> 10;     // 0=Q 1=K 2=V (block-uniform)
    float bj[4];
#pragma unroll
    for (int j = 0; j < 4; ++j) bj[j] = bias[o0 + (wn << 6) + (j << 4) + ln];

    if (which == 2) {               // V transposed: Vt[bh][d][s], 4 consecutive s -> b64
#pragma unroll
        for (int i = 0; i < 4; ++i) {
            const int m = m0 + (wm << 6) + (i << 4) + (g << 2);
            const int b = m >> 10, s = m & 1023;
#pragma unroll
            for (int j = 0; j < 4; ++j) {
                const int o = o0 + (wn << 6) + (j << 4) + ln;
                const int d = o & 63, hh = (o >> 6) & 15;
                ushortx4 pk;
#pragma unroll
                for (int q = 0; q < 4; ++q) pk[q] = f2b(acc[i][j][q] + bj[j]);
                *(ushortx4*)(Vt + (((size_t)((b << 4) + hh)) << 16) + (d << 10) + s) = pk;
            }
        }
    } else {
        unsigned short* dst = which ? Kb : Qb;
        const float sc = which ? 1.0f : 0.125f;   // fold 1/sqrt(64) into Q
#pragma unroll
        for (int i = 0; i < 4; ++i)
#pragma unroll
            for (int q = 0; q < 4; ++q) {
                const int m = m0 + (wm << 6) + (i << 4) + (g << 2) + q;
                const int b = m >> 10, s = m & 1023;
#pragma unroll
                for (int j = 0; j < 4; ++j) {
                    const int o = o0 + (wn << 6) + (j << 4) + ln;
                    const int d = o & 63, hh = (o >> 6) & 15;
                    dst[(((size_t)((b << 4) + hh)) << 16) + (s << 6) + d] =
                        f2b((acc[i][j][q] + bj[j]) * sc);
                }
            }
    }
}

// ---------------- k2: flash attention with rel-pos via band GEMMs ----------------
// block = 4 waves, handles (bh, 64 l-rows); wave w owns l-rows [16w,16w+16)
// per 64-key tile: S = QK^T (mfma) + diag(U) + diag(W);  U=Q@E_band^T, W=K@E_band^T
// LDS elems: Q[0,4096) K[4096,8192) E[8192,16384) (later V[8192,12288)+P[12288,16384))
//            U[16384,24576) W[24576,32768)   -> 64 KB total
__global__ __launch_bounds__(256, 2) void attn_mfma(
    const unsigned short* __restrict__ Qb, const unsigned short* __restrict__ Kb,
    const unsigned short* __restrict__ Vt, const unsigned short* __restrict__ Eb,
    const float* __restrict__ mask, float* __restrict__ outp)
{
    __shared__ unsigned short sm[32768];
    const int t = threadIdx.x, w = t >> 6;
    const int ln = t & 15, g = (t >> 4) & 3;
    const int bh = blockIdx.x >> 4;
    const int l0 = (blockIdx.x & 15) << 6;
    const int b = bh >> 4, h = bh & 15;
    const size_t hb = (size_t)bh << 16;
    const int x0 = (w << 4) + (g << 2);          // thread's base l-row

    // stage Q once (scaled bf16)
#pragma unroll
    for (int p = 0; p < 2; ++p) {
        const int idx = (p << 8) + t;
        const int row = idx >> 3;
        const int c = (idx & 7) ^ (row & 7);
        GLDS16(Qb + hb + ((size_t)(l0 + row) << 6) + (c << 3),
               (char*)sm + (p << 12) + (w << 10));
    }

    floatx4 O[4];
    float mr[4], lr[4];
#pragma unroll
    for (int dt = 0; dt < 4; ++dt) O[dt] = (floatx4){0.f, 0.f, 0.f, 0.f};
#pragma unroll
    for (int q = 0; q < 4; ++q) { mr[q] = -1e30f; lr[q] = 0.f; }

    short8 qa0, qa1;

    for (int r0 = 0; r0 < SEQ; r0 += 64) {
        __syncthreads();                         // A: prev PV reads done
#pragma unroll
        for (int p = 0; p < 2; ++p) {            // stage K
            const int idx = (p << 8) + t;
            const int row = idx >> 3;
            const int c = (idx & 7) ^ (row & 7);
            GLDS16(Kb + hb + ((size_t)(r0 + row) << 6) + (c << 3),
                   (char*)sm + 8192 + (p << 12) + (w << 10));
        }
        const int j0 = l0 - r0 + 960;            // E band start, in [0,1920]
#pragma unroll
        for (int p = 0; p < 4; ++p) {            // stage E band (128 rows)
            const int idx = (p << 8) + t;
            const int row = idx >> 3;
            const int c = (idx & 7) ^ (row & 7);
            GLDS16(Eb + ((size_t)(j0 + row) << 6) + (c << 3),
                   (char*)sm + 16384 + (p << 12) + (w << 10));
        }
        __syncthreads();                         // B: staging visible
        if (r0 == 0) {
            const int qr = (w << 4) + ln;
            qa0 = *(const short8*)&sm[TADDR(0, qr, g)];
            qa1 = *(const short8*)&sm[TADDR(0, qr, 4 + g)];
        }
        short8 kf[4][2];
#pragma unroll
        for (int j = 0; j < 4; ++j) {
            const int kr = (j << 4) + ln;
            kf[j][0] = *(const short8*)&sm[TADDR(4096, kr, g)];
            kf[j][1] = *(const short8*)&sm[TADDR(4096, kr, 4 + g)];
        }
        // W A-fragment (K rows of this wave) — explicit load, no dynamic reg indexing
        const int wr = (w << 4) + ln;
        const short8 ka0 = *(const short8*)&sm[TADDR(4096, wr, g)];
        const short8 ka1 = *(const short8*)&sm[TADDR(4096, wr, 4 + g)];

        floatx4 S[4];
#pragma unroll
        for (int j = 0; j < 4; ++j) {
            floatx4 z = (floatx4){0.f, 0.f, 0.f, 0.f};
            z = __builtin_amdgcn_mfma_f32_16x16x32_bf16(qa0, kf[j][0], z, 0, 0, 0);
            S[j] = __builtin_amdgcn_mfma_f32_16x16x32_bf16(qa1, kf[j][1], z, 0, 0, 0);
        }
#pragma unroll
        for (int dt = 0; dt < 8; ++dt) {
            const int er = (dt << 4) + ln;
            const short8 e0 = *(const short8*)&sm[TADDR(8192, er, g)];
            const short8 e1 = *(const short8*)&sm[TADDR(8192, er, 4 + g)];
            floatx4 z = (floatx4){0.f, 0.f, 0.f, 0.f};
            z = __builtin_amdgcn_mfma_f32_16x16x32_bf16(qa0, e0, z, 0, 0, 0);
            const floatx4 U = __builtin_amdgcn_mfma_f32_16x16x32_bf16(qa1, e1, z, 0, 0, 0);
            floatx4 z2 = (floatx4){0.f, 0.f, 0.f, 0.f};
            z2 = __builtin_amdgcn_mfma_f32_16x16x32_bf16(ka0, e0, z2, 0, 0, 0);
            const floatx4 Wv = __builtin_amdgcn_mfma_f32_16x16x32_bf16(ka1, e1, z2, 0, 0, 0);
            ushortx4 up, wp;
#pragma unroll
            for (int q = 0; q < 4; ++q) { up[q] = f2b(U[q]); wp[q] = f2b(Wv[q] * 0.125f); }
            const int dl = (dt << 4) + ln;
            *(ushortx4*)&sm[16384 + UWADDR(dl, x0)] = up;   // U[l,delta] as [delta][l]
            *(ushortx4*)&sm[24576 + UWADDR(dl, x0)] = wp;   // W[r,delta] as [delta][r]
        }
        __syncthreads();                         // C: U/W visible; E dead
#pragma unroll
        for (int p = 0; p < 2; ++p) {            // stage V (transposed) over dead E
            const int idx = (p << 8) + t;
            const int row = idx >> 3;            // = d
            const int c = (idx & 7) ^ (row & 7);
            GLDS16(Vt + hb + ((size_t)row << 10) + r0 + (c << 3),
                   (char*)sm + 16384 + (p << 12) + (w << 10));
        }
        // assemble scores + online softmax
        float Pw[4][4];
#pragma unroll
        for (int j = 0; j < 4; ++j) {
            const int rr = (j << 4) + ln;
            const float mk = mask[(b << 10) + r0 + rr];
#pragma unroll
            for (int q = 0; q < 4; ++q) {
                const int l = x0 + q;
                const int dl = l - rr + 63;      // in [0,126]
                S[j][q] += b2f(sm[16384 + UWADDR(dl, l)]) +
                           b2f(sm[24576 + UWADDR(dl, rr)]) + mk;
            }
        }
#pragma unroll
        for (int q = 0; q < 4; ++q) {
            float tm = fmaxf(fmaxf(S[0][q], S[1][q]), fmaxf(S[2][q], S[3][q]));
            tm = fmaxf(tm, __shfl_xor(tm, 1));
            tm = fmaxf(tm, __shfl_xor(tm, 2));
            tm = fmaxf(tm, __shfl_xor(tm, 4));
            tm = fmaxf(tm, __shfl_xor(tm, 8));
            const float mnew = fmaxf(mr[q], tm);
            const float al = __expf(mr[q] - mnew);
            float sum = 0.f;
#pragma unroll
            for (int j = 0; j < 4; ++j) {
                const float p = __expf(S[j][q] - mnew);
                Pw[j][q] = p; sum += p;
            }
            sum += __shfl_xor(sum, 1);
            sum += __shfl_xor(sum, 2);
            sum += __shfl_xor(sum, 4);
            sum += __shfl_xor(sum, 8);
            lr[q] = lr[q] * al + sum;
            mr[q] = mnew;
#pragma unroll
            for (int dt = 0; dt < 4; ++dt) O[dt][q] *= al;
        }
        // write P (bf16) into [l][r] swizzled tile at elems 12288
#pragma unroll
        for (int j = 0; j < 4; ++j) {
            const int rr = (j << 4) + ln;
#pragma unroll
            for (int q = 0; q < 4; ++q) {
                const int l = x0 + q;
                sm[12288 + (l << 6) + ((((rr >> 3) ^ (l & 7)) << 3)) + (rr & 7)] = f2b(Pw[j][q]);
            }
        }
        __syncthreads();                         // D: P + V visible
        const int pr = (w << 4) + ln;
        const short8 pa0 = *(const short8*)&sm[TADDR(12288, pr, g)];
        const short8 pa1 = *(const short8*)&sm[TADDR(12288, pr, 4 + g)];
#pragma unroll
        for (int dt = 0; dt < 4; ++dt) {
            const int vr = (dt << 4) + ln;       // = d row of V^T tile
            const short8 v0 = *(const short8*)&sm[TADDR(8192, vr, g)];
            const short8 v1 = *(const short8*)&sm[TADDR(8192, vr, 4 + g)];
            O[dt] = __builtin_amdgcn_mfma_f32_16x16x32_bf16(pa0, v0, O[dt], 0, 0, 0);
            O[dt] = __builtin_amdgcn_mfma_f32_16x16x32_bf16(pa1, v1, O[dt], 0, 0, 0);
        }
    }
    // normalize + write out[b, l0+l, h*64 + d]
#pragma unroll
    for (int dt = 0; dt < 4; ++dt)
#pragma unroll
        for (int q = 0; q < 4; ++q) {
            const int l = x0 + q;
            outp[((size_t)b << 20) + ((size_t)(l0 + l) << 10) + (h << 6) + (dt << 4) + ln]
                = O[dt][q] / lr[q];
        }
}

extern "C" void kernel_launch(void* const* d_in, const int* in_sizes, int n_in,
                              void* d_out, int out_size, void* d_ws, size_t ws_size,
                              hipStream_t stream)
{
    const float* hs   = (const float*)d_in[0];   // [4,1024,1024]
    const float* qkvw = (const float*)d_in[1];   // [3072,1024]
    const float* qkvb = (const float*)d_in[2];   // [3072]
    const float* demb = (const float*)d_in[3];   // [2047,64]
    const float* mask = (const float*)d_in[4];   // [4,1,1,1024]
    float* out = (float*)d_out;

    char* ws = (char*)d_ws;
    unsigned short* hsb = (unsigned short*)(ws);              // 8,388,608 B
    unsigned short* Wb  = (unsigned short*)(ws + 8388608);    // 6,291,456 B
    unsigned short* Eb  = (unsigned short*)(ws + 14680064);   //   262,016 B
    unsigned short* Qb  = (unsigned short*)(ws + 14942208);   // 8,388,608 B (pre-scaled)
    unsigned short* Kb  = (unsigned short*)(ws + 23330816);   // 8,388,608 B
    unsigned short* Vt  = (unsigned short*)(ws + 31719424);   // 8,388,608 B (transposed)

    cast_kernel<<<2048, 256, 0, stream>>>(hs, qkvw, demb, hsb, Wb, Eb);
    qkv_gemm<<<dim3(24, 32), 256, 0, stream>>>(hsb, Wb, qkvb, Qb, Kb, Vt);
    attn_mfma<<<1024, 256, 0, stream>>>(Qb, Kb, Vt, Eb, mask, out);
}